// Round 8
// baseline (333.168 us; speedup 1.0000x reference)
//
#include <hip/hip_runtime.h>

#define HS   512
#define WSZ  512
#define NC   64
#define HW   (HS * WSZ)
#define KCAP 12       // inverted-map bin capacity (Poisson(1); max over 262k bins ~9-10)
#define LCAP 32       // per-target list capacity (Poisson(9); P(>32) ~ 3e-5 overall)
#define HWP  (HW + 4) // slice stride in uint4 (one sentinel record + pad)
#define SENT 0x40000  // sentinel q == HW -> zeroed record in every slice

typedef unsigned int uint;
typedef unsigned short ushort;

// float -> bf16 (round-to-nearest-even), raw bits
__device__ __forceinline__ ushort f2bf(float f) {
    uint b = __float_as_uint(f);
    return (ushort)((b + 0x7FFFu + ((b >> 16) & 1u)) >> 16);
}

// ---------------------------------------------------------------------------
// A: FUSED prep + fill.  Blocks [0,4096): transpose ref (C,H,W) f32 ->
// OCTET-MAJOR slices refoct[q][pixel] (uint4 = 8 bf16 channels, 16B/pixel).
// A channel-octet slice is 4 MiB == one XCD's L2: gather blocks specialized
// by octet (blockIdx%8 -> XCD round-robin) keep their slice L2-resident,
// which is the whole point of this round.  Blocks [4096,5120): invert nnf_rs
// into bins (1 atomic/pixel; split cnt/slots arrays, R3-R6-proven).  Block
// 4096 zeroes each slice's sentinel record.  cnt zeroed by hipMemsetAsync.
// ---------------------------------------------------------------------------
__global__ __launch_bounds__(256) void prep_fill_oct(
    const float4* __restrict__ ref4, uint4* __restrict__ refoct,
    const int2* __restrict__ nnf_rs, int* __restrict__ cnt,
    int* __restrict__ slots)
{
    __shared__ float lds[64 * 65];
    const int tid = threadIdx.x;

    if (blockIdx.x < 4096) {
        const int p0 = blockIdx.x * 64;        // 64 pixels / tile
#pragma unroll
        for (int k = 0; k < 4; ++k) {
            int e  = k * 256 + tid;            // 1024 float4 per tile
            int c  = e >> 4;                   // channel
            int i4 = e & 15;                   // pixel quad
            float4 v = ref4[(size_t)c * (HW / 4) + (p0 >> 2) + i4];
            lds[(i4 * 4 + 0) * 65 + c] = v.x;
            lds[(i4 * 4 + 1) * 65 + c] = v.y;
            lds[(i4 * 4 + 2) * 65 + c] = v.z;
            lds[(i4 * 4 + 3) * 65 + c] = v.w;
        }
        __syncthreads();
#pragma unroll
        for (int k = 0; k < 2; ++k) {
            int e = k * 256 + tid;             // 512 slice-records per tile
            int q = e >> 6;                    // octet 0..7
            int i = e & 63;                    // pixel 0..63 (consec tid ->
            const float* row = &lds[i * 65 + 8 * q];   //  coalesced 1KB runs)
            uint4 u;
            u.x = (uint)f2bf(row[0]) | ((uint)f2bf(row[1]) << 16);
            u.y = (uint)f2bf(row[2]) | ((uint)f2bf(row[3]) << 16);
            u.z = (uint)f2bf(row[4]) | ((uint)f2bf(row[5]) << 16);
            u.w = (uint)f2bf(row[6]) | ((uint)f2bf(row[7]) << 16);
            refoct[(size_t)q * HWP + p0 + i] = u;
        }
    } else {
        if (blockIdx.x == 4096 && tid < 8) {   // zero per-slice sentinel
            uint4 z; z.x = 0u; z.y = 0u; z.z = 0u; z.w = 0u;
            refoct[(size_t)tid * HWP + HW] = z;
        }
        const int r = (blockIdx.x - 4096) * 256 + tid;
        const int2 s = nnf_rs[r];              // (sy, sx) in [0,512)
        const int bin = (s.x << 9) | s.y;
        const int pos = atomicAdd(&cnt[bin], 1);
        if (pos < KCAP) slots[bin * KCAP + pos] = r;
    }
}

// ---------------------------------------------------------------------------
// B: expand — phase E (R3-proven LDS expansion) done ONCE per target, output
// to global glists (chunk-local rows of 32 ints, SENT-padded to the next
// multiple of 8) + gcnt.  32 targets/block; chunk = half the image (keeps
// glists at 16 MiB so total workspace stays under the proven 65 MiB).
// ---------------------------------------------------------------------------
__global__ __launch_bounds__(256) void expand(
    const int* __restrict__ cnt, const int* __restrict__ slots,
    int* __restrict__ gcnt, int* __restrict__ glists, const int chunk_row0)
{
    __shared__ __align__(16) int lists[32][32];
    __shared__ int lcnt[32];
    __shared__ int bcnt[102];            // 3 rows x 34 cols of neighbor bins

    const int tid = threadIdx.x;
    const int t0  = (chunk_row0 << 9) + blockIdx.x * 32;
    const int ty0 = t0 >> 9, tx0 = t0 & 511;

    if (tid < 32) lcnt[tid] = 0;
    if (tid < 102) {
        const int jr = tid / 34, jc = tid - jr * 34;
        const int sy = ty0 + jr - 1, sx = tx0 + jc - 1;
        const bool sv = ((unsigned)sy < 512u) & ((unsigned)sx < 512u);
        const int sidx = ((sy & 511) << 9) | (sx & 511);
        bcnt[tid] = sv ? min(cnt[sidx], KCAP) : 0;
    }
    {
        int4 s4; s4.x = SENT; s4.y = SENT; s4.z = SENT; s4.w = SENT;
        ((int4*)lists)[tid] = s4;        // 256 int4 == 32x32 ints exactly
    }
    __syncthreads();

    for (int p = tid; p < 306; p += 256) {
        const int j  = p / 3;
        const int di = p - j * 3;              // dx = di-1
        const int jr = j / 34, jc = j - jr * 34;
        const int dy = 1 - jr;                 // unique dy for this bin row
        const int dx = di - 1;
        const int lt = jc - 1 + dx;            // local target index
        const int c  = bcnt[j];
        if (((unsigned)lt < 32u) && (c > 0)) {
            const int sy = ty0 + jr - 1, sx = tx0 + jc - 1;
            const int sbase = ((sy << 9) | sx) * KCAP;
            for (int e2 = 0; e2 < c; ++e2) {
                const int r  = slots[sbase + e2];
                const int qy = (r >> 9) + dy, qx = (r & 511) + dx;
                if (((unsigned)qy < 512u) & ((unsigned)qx < 512u)) {
                    const int pos = atomicAdd(&lcnt[lt], 1);
                    if (pos < LCAP) lists[lt][pos] = (qy << 9) | qx;
                }
            }
        }
    }
    __syncthreads();

    // write out: 8 threads per target, one int4 quad each
    const int lt = tid >> 3, j = tid & 7;
    const int Sreal = min(lcnt[lt], LCAP);
    const int S8 = (Sreal + 7) & ~7;
    const size_t lloc = (size_t)blockIdx.x * 32 + lt;   // chunk-local target
    if (j == 0) gcnt[t0 + lt] = Sreal;
    if (j * 4 < S8)
        *(int4*)(glists + (lloc << 5) + (j << 2)) = ((const int4*)lists[lt])[j];
}

// ---------------------------------------------------------------------------
// C: gather_oct — 256 targets x ONE channel octet per block.
// octet = blockIdx%8: with the empirical round-robin blockIdx->XCD mapping,
// each XCD touches only its 4 MiB slice -> record reads become L2 hits
// (vs 268 MB of HBM fetch in R4-R7).  If the mapping assumption fails this
// degrades to current perf, never correctness.  1 thread/target, 16B slice
// loads, no LDS atomics; pass 2 is the maskless 8-deep walk fed by glists.
// ---------------------------------------------------------------------------
__global__ __launch_bounds__(256) void gather_oct(
    const uint4* __restrict__ refoct,
    const int2*  __restrict__ nnf_sr,
    const int*   __restrict__ gcnt,
    const int*   __restrict__ glists,
    float* __restrict__ out,
    const int chunk_row0)
{
    const float ws = 1.0f / 262144.0f;   // 2^-18 exact
    const float wr = 2.0f / 262144.0f;   // 2^-17 exact

    __shared__ int2 snn[3 * 258];        // nnf_sr rows ty0-1..+1, cols tx0-1..+256

    const int tid = threadIdx.x;
    const int q   = blockIdx.x & 7;      // octet -> XCD affinity
    const int ts  = blockIdx.x >> 3;     // target-set [0,512) in chunk
    const int ty0 = chunk_row0 + (ts >> 1);
    const int tx0 = (ts & 1) << 8;

    for (int p = tid; p < 774; p += 256) {
        const int jr = p / 258, jc = p - jr * 258;
        const int sy = ty0 + jr - 1, sx = tx0 + jc - 1;
        const int sidx = ((sy & 511) << 9) | (sx & 511);   // clamped
        snn[p] = nnf_sr[sidx];           // garbage ok out-of-range (masked)
    }
    __syncthreads();

    const int lloc = (ts << 8) + tid;                 // chunk-local target
    const int t    = (chunk_row0 << 9) + lloc;        // global target
    const uint4* __restrict__ slice = refoct + (size_t)q * HWP;
    const int*   __restrict__ lb    = glists + ((size_t)lloc << 5);

    const int Sreal = gcnt[t];
    const int S8    = (Sreal + 7) & ~7;
    int4 e = *(const int4*)(lb);         // first quads (garbage if S8==0,
    int4 f = *(const int4*)(lb + 4);     //  never used then)

    float a0=0,a1=0,a2=0,a3=0,a4=0,a5=0,a6=0,a7=0;
    int nv = 0;

    // ---- pass 1 index calc: all 9 tap indices, no loads yet ----
#define TAPQ(i, dy, dx)                                                       \
    int q##i; {                                                               \
        const bool rv = ((unsigned)(ty0 - (dy)) < 512u);      /* uniform */   \
        const bool cv = ((unsigned)(tx0 + tid - (dx)) < 512u);                \
        const int2 nn = snn[(1 - (dy)) * 258 + (tid - (dx) + 1)];             \
        const int qy = nn.x + (dy), qx = nn.y + (dx);                         \
        const bool v = rv & cv &                                              \
                       ((unsigned)qy < 512u) & ((unsigned)qx < 512u);         \
        q##i = v ? ((qy << 9) | qx) : SENT;                                   \
        nv += v ? 1 : 0;                                                      \
    }

    TAPQ(0, -1, -1)  TAPQ(1, -1, 0)  TAPQ(2, -1, 1)
    TAPQ(3,  0, -1)  TAPQ(4,  0, 0)  TAPQ(5,  0, 1)
    TAPQ(6,  1, -1)  TAPQ(7,  1, 0)  TAPQ(8,  1, 1)
#undef TAPQ

    // ---- pass 1 load burst: 9 slice reads (16B each) ----
    const uint4 u0 = slice[(size_t)q0];
    const uint4 u1 = slice[(size_t)q1];
    const uint4 u2 = slice[(size_t)q2];
    const uint4 u3 = slice[(size_t)q3];
    const uint4 u4 = slice[(size_t)q4];
    const uint4 u5 = slice[(size_t)q5];
    const uint4 u6 = slice[(size_t)q6];
    const uint4 u7 = slice[(size_t)q7];
    const uint4 u8 = slice[(size_t)q8];

    __builtin_amdgcn_sched_barrier(0);   // keep the burst issued together

#define UNPACK(u_)                                                            \
    {                                                                         \
        a0 += __uint_as_float(u_.x << 16);                                    \
        a1 += __uint_as_float(u_.x & 0xffff0000u);                            \
        a2 += __uint_as_float(u_.y << 16);                                    \
        a3 += __uint_as_float(u_.y & 0xffff0000u);                            \
        a4 += __uint_as_float(u_.z << 16);                                    \
        a5 += __uint_as_float(u_.z & 0xffff0000u);                            \
        a6 += __uint_as_float(u_.w << 16);                                    \
        a7 += __uint_as_float(u_.w & 0xffff0000u);                            \
    }

    UNPACK(u0) UNPACK(u1) UNPACK(u2) UNPACK(u3) UNPACK(u4)
    UNPACK(u5) UNPACK(u6) UNPACK(u7) UNPACK(u8)

    // fold pass-1 into pass-2 scale domain: ws = 0.5*wr (exact pow2 scale)
    a0 *= 0.5f; a1 *= 0.5f; a2 *= 0.5f; a3 *= 0.5f;
    a4 *= 0.5f; a5 *= 0.5f; a6 *= 0.5f; a7 *= 0.5f;

    // ---- pass 2: 8-deep pipelined maskless walk (tails are SENT=zero) ----
    // Last-iteration prefetch reads up to lb[39]: inside the next row or the
    // 256B glists tail pad; values discarded.
    for (int s = 0; s < S8; s += 8) {
        const uint4 v0 = slice[(size_t)(e.x)];
        const uint4 v1 = slice[(size_t)(e.y)];
        const uint4 v2 = slice[(size_t)(e.z)];
        const uint4 v3 = slice[(size_t)(e.w)];
        const uint4 v4 = slice[(size_t)(f.x)];
        const uint4 v5 = slice[(size_t)(f.y)];
        const uint4 v6 = slice[(size_t)(f.z)];
        const uint4 v7 = slice[(size_t)(f.w)];
        const int4 en = *(const int4*)(lb + s + 8);
        const int4 fn = *(const int4*)(lb + s + 12);
        __builtin_amdgcn_sched_barrier(0);
        UNPACK(v0) UNPACK(v1) UNPACK(v2) UNPACK(v3)
        UNPACK(v4) UNPACK(v5) UNPACK(v6) UNPACK(v7)
        e = en; f = fn;
    }
#undef UNPACK

    // ---- epilogue: w = ws*nv + wr*Sreal (exact); plain stores (NOT nt:
    // R7 proved nt breaks L2 write-combining, WRITE 66->121 MB) ----
    const float wsum = ws * (float)nv + wr * (float)Sreal;   // nv>=1 always
    const float sc = wr / wsum;
    size_t o = (size_t)(8 * q) * HW + t;
    out[o]                = a0 * sc;
    out[o + 1*(size_t)HW] = a1 * sc;
    out[o + 2*(size_t)HW] = a2 * sc;
    out[o + 3*(size_t)HW] = a3 * sc;
    out[o + 4*(size_t)HW] = a4 * sc;
    out[o + 5*(size_t)HW] = a5 * sc;
    out[o + 6*(size_t)HW] = a6 * sc;
    out[o + 7*(size_t)HW] = a7 * sc;
}

// ===========================================================================
// Fallback (tiny workspace): bins only, gather channel-major f32 ref with
// the SEL-chain walk.  (KCAP-consistent slots stride.)
// ===========================================================================
__global__ __launch_bounds__(256) void fill_bins(
    const int2* __restrict__ nnf_rs, int* __restrict__ cnt,
    int* __restrict__ slots)
{
    int r = blockIdx.x * 256 + threadIdx.x;
    int2 s = nnf_rs[r];
    int bin = (s.x << 9) | s.y;
    int pos = atomicAdd(&cnt[bin], 1);
    if (pos < KCAP) slots[bin * KCAP + pos] = r;
}

__global__ __launch_bounds__(256) void gather8_f32(
    const float* __restrict__ reff,
    const int2*  __restrict__ nnf_sr,
    const int*   __restrict__ cnt,
    const int*   __restrict__ slots,
    float* __restrict__ out)
{
    const float ws = 1.0f / 262144.0f;
    const float wr = 2.0f / 262144.0f;

    const int tid = threadIdx.x;
    const int k   = tid & 7;
    const int t   = blockIdx.x * 32 + (tid >> 3);
    const int ty  = t >> 9, tx = t & 511;

    float a0=0,a1=0,a2=0,a3=0,a4=0,a5=0,a6=0,a7=0, w=0.f;

#define ACCUM(qv, mv)                                                         \
    {                                                                         \
        const int   q_ = (qv);                                                \
        const float m_ = (mv);                                                \
        const size_t c0_ = (size_t)(8 * k) * HW + q_;                         \
        a0 += reff[c0_ + 0*(size_t)HW] * m_;                                  \
        a1 += reff[c0_ + 1*(size_t)HW] * m_;                                  \
        a2 += reff[c0_ + 2*(size_t)HW] * m_;                                  \
        a3 += reff[c0_ + 3*(size_t)HW] * m_;                                  \
        a4 += reff[c0_ + 4*(size_t)HW] * m_;                                  \
        a5 += reff[c0_ + 5*(size_t)HW] * m_;                                  \
        a6 += reff[c0_ + 6*(size_t)HW] * m_;                                  \
        a7 += reff[c0_ + 7*(size_t)HW] * m_;                                  \
        w += m_;                                                              \
    }

    int mt0,mt1,mt2,mt3,mt4,mt5,mt6,mt7,mt8;
    int run = 0;

#define TAP(i, dy, dx)                                                        \
    {                                                                         \
        const int sy = ty - (dy), sx = tx - (dx);                             \
        const bool sval = ((unsigned)sy < 512u) & ((unsigned)sx < 512u);      \
        const int sidx = ((sy & 511) << 9) | (sx & 511);                      \
        mt##i = (sidx << 12) | ((i) << 8) | run;                              \
        const int c = cnt[sidx];                                              \
        run += sval ? min(c, KCAP) : 0;                                       \
        const int2 nn = nnf_sr[sidx];                                         \
        const int qy = nn.x + (dy), qx = nn.y + (dx);                         \
        const bool v = sval & ((unsigned)qy < 512u) & ((unsigned)qx < 512u);  \
        ACCUM((((qy & 511) << 9) | (qx & 511)), v ? ws : 0.f)                 \
    }

    TAP(0, -1, -1)  TAP(1, -1, 0)  TAP(2, -1, 1)
    TAP(3,  0, -1)  TAP(4,  0, 0)  TAP(5,  0, 1)
    TAP(6,  1, -1)  TAP(7,  1, 0)  TAP(8,  1, 1)
#undef TAP

    const int S = run;

#define SEL(i)  m_ = (s_ >= (mt##i & 255)) ? mt##i : m_;
#define ENTRY(sv)                                                             \
    {                                                                         \
        const int s_ = (sv);                                                  \
        int m_ = mt0;                                                         \
        SEL(1) SEL(2) SEL(3) SEL(4) SEL(5) SEL(6) SEL(7) SEL(8)               \
        const int off_ = m_ & 255;                                            \
        const int ii_  = (m_ >> 8) & 15;                                      \
        const int bs_  = (m_ >> 12) * KCAP;                                   \
        const int idx_ = min(s_ - off_, KCAP - 1);                            \
        const int e_   = slots[bs_ + idx_];                                   \
        const int ry_  = (e_ >> 9) & 511, rx_ = e_ & 511;                     \
        const int dyp_ = (ii_ * 11) >> 5;                                     \
        const int dy_  = dyp_ - 1, dx_ = ii_ - 3 * dyp_ - 1;                  \
        const int qy_  = ry_ + dy_, qx_ = rx_ + dx_;                          \
        const bool v_  = (s_ < S) &                                           \
                         ((unsigned)qy_ < 512u) & ((unsigned)qx_ < 512u);     \
        ACCUM((((qy_ & 511) << 9) | (qx_ & 511)), v_ ? wr : 0.f)              \
    }

    for (int s = 0; s < S; s += 2) {
        ENTRY(s)
        ENTRY(s + 1)
    }
#undef ENTRY
#undef SEL
#undef ACCUM

    if (w == 0.f) w = 1.f;
    const float inv = 1.f / w;
    size_t o = (size_t)(8 * k) * HW + t;
    out[o]                = a0 * inv;
    out[o + 1*(size_t)HW] = a1 * inv;
    out[o + 2*(size_t)HW] = a2 * inv;
    out[o + 3*(size_t)HW] = a3 * inv;
    out[o + 4*(size_t)HW] = a4 * inv;
    out[o + 5*(size_t)HW] = a5 * inv;
    out[o + 6*(size_t)HW] = a6 * inv;
    out[o + 7*(size_t)HW] = a7 * inv;
}

extern "C" void kernel_launch(void* const* d_in, const int* in_sizes, int n_in,
                              void* d_out, int out_size, void* d_ws, size_t ws_size,
                              hipStream_t stream)
{
    const float* ref    = (const float*)d_in[0];
    const int2*  nnf_sr = (const int2*)d_in[1];
    const int2*  nnf_rs = (const int2*)d_in[2];
    float* out = (float*)d_out;

    char* wsb = (char*)d_ws;
    const size_t refoct_bytes = (size_t)8 * HWP * 16;        // 32.0 MiB
    const size_t cnt_bytes    = (size_t)HW * 4;              //  1   MiB
    const size_t slot_bytes   = (size_t)HW * KCAP * 4;       // 12   MiB
    const size_t gcnt_bytes   = (size_t)HW * 4;              //  1   MiB
    const size_t glist_bytes  = (size_t)(HW / 2) * LCAP * 4 + 256;  // 16 MiB
    const size_t total = refoct_bytes + cnt_bytes + slot_bytes
                       + gcnt_bytes + glist_bytes;           // ~62.0 MiB

    if (ws_size >= total) {   // < the 65 MiB proven available in round 2
        uint4* refoct = (uint4*)wsb;
        int*   cntp   = (int*)(wsb + refoct_bytes);
        int*   slots  = (int*)(wsb + refoct_bytes + cnt_bytes);
        int*   gcnt   = (int*)(wsb + refoct_bytes + cnt_bytes + slot_bytes);
        int*   glists = (int*)(wsb + refoct_bytes + cnt_bytes + slot_bytes
                                   + gcnt_bytes);

        hipMemsetAsync(cntp, 0, cnt_bytes, stream);
        prep_fill_oct<<<4096 + HW / 256, 256, 0, stream>>>(
            (const float4*)ref, refoct, nnf_rs, cntp, slots);
        // chunk 0: rows [0,256)
        expand    <<<4096, 256, 0, stream>>>(cntp, slots, gcnt, glists, 0);
        gather_oct<<<4096, 256, 0, stream>>>(refoct, nnf_sr, gcnt, glists, out, 0);
        // chunk 1: rows [256,512)
        expand    <<<4096, 256, 0, stream>>>(cntp, slots, gcnt, glists, 256);
        gather_oct<<<4096, 256, 0, stream>>>(refoct, nnf_sr, gcnt, glists, out, 256);
    } else {
        // fallback: bins only, gather channel-major f32 ref directly
        int* cntp  = (int*)wsb;
        int* slots = cntp + HW;
        hipMemsetAsync(cntp, 0, cnt_bytes, stream);
        fill_bins<<<HW / 256, 256, 0, stream>>>(nnf_rs, cntp, slots);
        gather8_f32<<<HW / 32, 256, 0, stream>>>(ref, nnf_sr, cntp, slots, out);
    }
}

// Round 10
// 217.077 us; speedup vs baseline: 1.5348x; 1.5348x over previous
//
#include <hip/hip_runtime.h>

#define HS   512
#define WSZ  512
#define NC   64
#define HW   (HS * WSZ)
#define KCAP 16       // inverted-map bin capacity (Poisson(1)/bin; P(>16) ~ 1e-14)
#define NINL 7        // inline slots per bin record (binrec = {cnt, s0..s6})
#define NOVF (KCAP - NINL)
#define LCAP 32       // per-target LDS list capacity (Poisson(9); P(>32) ~ 3e-5 overall)
#define LROW 40       // list row stride (ints): 32 entries + 8 pad for prefetch
#define SENT 0x40000  // sentinel q -> zeroed pixel record appended at refu4[HW]

typedef unsigned int uint;
typedef unsigned short ushort;
typedef float f32x4 __attribute__((ext_vector_type(4)));   // clang vector: OK
                                                           // for nt builtin
// float -> bf16 (round-to-nearest-even), raw bits
__device__ __forceinline__ ushort f2bf(float f) {
    uint b = __float_as_uint(f);
    return (ushort)((b + 0x7FFFu + ((b >> 16) & 1u)) >> 16);
}

// ---------------------------------------------------------------------------
// FUSED prep + fill (byte-identical to R7 — passing).  Blocks [0,4096):
// transpose ref (C,H,W) f32 -> refu4 (H*W+1, 8) uint4 (packed bf16 pairs,
// 128B/pixel).  Blocks [4096,5120): invert nnf_rs into INTERLEAVED bin
// records binrec[bin] = {cnt, slot0..slot6} (one 64B line/bin) + rare ovf.
// Entry order preserved (pos<7 inline, then ovf) => summation order and
// output bits identical to split arrays.  binrec zeroed by hipMemsetAsync.
// ---------------------------------------------------------------------------
__global__ __launch_bounds__(256) void prep_fill(
    const float4* __restrict__ ref4, uint4* __restrict__ refu4,
    const int2* __restrict__ nnf_rs, int* __restrict__ binrec,
    int* __restrict__ ovf)
{
    __shared__ float lds[64 * 65];
    const int tid = threadIdx.x;

    if (blockIdx.x < 4096) {
        const int p0 = blockIdx.x * 64;        // 64 pixels / tile
#pragma unroll
        for (int k = 0; k < 4; ++k) {
            int e  = k * 256 + tid;            // 1024 float4 per tile
            int c  = e >> 4;                   // channel
            int i4 = e & 15;                   // pixel quad
            float4 v = ref4[(size_t)c * (HW / 4) + (p0 >> 2) + i4];
            lds[(i4 * 4 + 0) * 65 + c] = v.x;
            lds[(i4 * 4 + 1) * 65 + c] = v.y;
            lds[(i4 * 4 + 2) * 65 + c] = v.z;
            lds[(i4 * 4 + 3) * 65 + c] = v.w;
        }
        __syncthreads();
#pragma unroll
        for (int k = 0; k < 2; ++k) {
            int e = k * 256 + tid;             // 512 uint4 per tile
            int i = e >> 3;                    // pixel
            int q = e & 7;                     // channel octet
            const float* row = &lds[i * 65 + 8 * q];
            uint4 u;
            u.x = (uint)f2bf(row[0]) | ((uint)f2bf(row[1]) << 16);
            u.y = (uint)f2bf(row[2]) | ((uint)f2bf(row[3]) << 16);
            u.z = (uint)f2bf(row[4]) | ((uint)f2bf(row[5]) << 16);
            u.w = (uint)f2bf(row[6]) | ((uint)f2bf(row[7]) << 16);
            refu4[(size_t)(p0 + i) * 8 + q] = u;
        }
    } else {
        if (blockIdx.x == 4096 && tid < 8) {   // zero the sentinel record
            uint4 z; z.x = 0u; z.y = 0u; z.z = 0u; z.w = 0u;
            refu4[(size_t)HW * 8 + tid] = z;
        }
        const int r = (blockIdx.x - 4096) * 256 + tid;
        const int2 s = nnf_rs[r];              // (sy, sx), values in [0,512)
        const int bin = (s.x << 9) | s.y;
        const int pos = atomicAdd(&binrec[bin << 3], 1);
        if (pos < NINL)      binrec[(bin << 3) + 1 + pos] = r;
        else if (pos < KCAP) ovf[bin * NOVF + (pos - NINL)] = r;
    }
}

// ---------------------------------------------------------------------------
// gather_lds: 32 targets/block, 8 lanes/target over channel octets.
// Body identical to R6/R7 (97.4us best).  ONE change vs R7: the epilogue is
// an LDS transpose so each wave's store instruction writes 8x128B contiguous
// full-line runs, then NON-TEMPORAL f32x4 stores.  R7 proved scalar nt
// (32B partial lines) doubles WRITE to 121MB; full-line nt cannot split
// lines, avoids L2 write-allocate fill reads, and stops 66MB of output from
// evicting record lines out of L2.
// ---------------------------------------------------------------------------
__global__ __launch_bounds__(256) void gather_lds(
    const uint4* __restrict__ refu4,
    const int2*  __restrict__ nnf_sr,
    const int*   __restrict__ binrec,
    const int*   __restrict__ ovf,
    float* __restrict__ out)
{
    const float ws = 1.0f / 262144.0f;   // 2^-18 exact
    const float wr = 2.0f / 262144.0f;   // 2^-17 exact

    __shared__ __align__(16) int lists[32][LROW];
    __shared__ int  lcnt[32];
    __shared__ int  bcnt[102];           // 3 rows x 34 cols of neighbor bins
    __shared__ int2 snn[102];            // nnf_sr staged for the same bins
    __shared__ float obuf[64][33];       // transpose tile; (c+lt)%32 banks ->
                                         // 2-way on write (free, m136)

    const int tid = threadIdx.x;
    const int t0  = blockIdx.x * 32;     // 32 targets, all in row ty0
    const int ty0 = t0 >> 9, tx0 = t0 & 511;

    // ---- phase E0: stage bin counts + nnf_sr, SENT-fill lists ----
    if (tid < 32) lcnt[tid] = 0;
    if (tid < 102) {
        const int jr = tid / 34, jc = tid - jr * 34;
        const int sy = ty0 + jr - 1, sx = tx0 + jc - 1;
        const bool sv = ((unsigned)sy < 512u) & ((unsigned)sx < 512u);
        const int sidx = ((sy & 511) << 9) | (sx & 511);   // clamped-in-range
        bcnt[tid] = sv ? min(binrec[sidx << 3], KCAP) : 0;
        snn[tid]  = nnf_sr[sidx];        // garbage ok when !sv (masked later)
    }
    {
        int4 s4; s4.x = SENT; s4.y = SENT; s4.z = SENT; s4.w = SENT;
        for (int p = tid; p < 32 * LROW / 4; p += 256)     // 320 int4
            ((int4*)lists)[p] = s4;
    }
    __syncthreads();

    // ---- phase E1: expand 102 bins x 3 dx-taps into per-target lists ----
    for (int p = tid; p < 306; p += 256) {
        const int j  = p / 3;
        const int di = p - j * 3;              // dx = di-1
        const int jr = j / 34, jc = j - jr * 34;
        const int dy = 1 - jr;                 // unique dy for this bin row
        const int dx = di - 1;
        const int lt = jc - 1 + dx;            // local target index
        const int c  = bcnt[j];
        if (((unsigned)lt < 32u) && (c > 0)) {
            const int sy = ty0 + jr - 1, sx = tx0 + jc - 1;
            const int sidx = (sy << 9) | sx;
            const int sb8  = sidx << 3;
            for (int e2 = 0; e2 < c; ++e2) {
                const int r = (e2 < NINL) ? binrec[sb8 + 1 + e2]
                                          : ovf[sidx * NOVF + (e2 - NINL)];
                const int qy = (r >> 9) + dy, qx = (r & 511) + dx;
                if (((unsigned)qy < 512u) & ((unsigned)qx < 512u)) {
                    const int pos = atomicAdd(&lcnt[lt], 1);
                    if (pos < LCAP) lists[lt][pos] = (qy << 9) | qx;
                }
            }
        }
    }
    __syncthreads();

    // ---- per-thread identity ----
    const int k  = tid & 7;                    // channel octet
    const int lt = tid >> 3;                   // local target
    const uint4* __restrict__ refk = refu4 + k;

    float a0=0,a1=0,a2=0,a3=0,a4=0,a5=0,a6=0,a7=0;
    int nv = 0;

    // ---- pass 1 index calc: all 9 tap indices, no loads yet ----
#define TAPQ(i, dy, dx)                                                       \
    int q##i; {                                                               \
        const bool rv = ((unsigned)(ty0 - (dy)) < 512u);      /* uniform */   \
        const bool cv = ((unsigned)(tx0 + lt - (dx)) < 512u);                 \
        const int2 nn = snn[(1 - (dy)) * 34 + (lt - (dx) + 1)];               \
        const int qy = nn.x + (dy), qx = nn.y + (dx);                         \
        const bool v = rv & cv &                                              \
                       ((unsigned)qy < 512u) & ((unsigned)qx < 512u);         \
        q##i = v ? ((qy << 9) | qx) : SENT;                                   \
        nv += v ? 1 : 0;                                                      \
    }

    TAPQ(0, -1, -1)  TAPQ(1, -1, 0)  TAPQ(2, -1, 1)
    TAPQ(3,  0, -1)  TAPQ(4,  0, 0)  TAPQ(5,  0, 1)
    TAPQ(6,  1, -1)  TAPQ(7,  1, 0)  TAPQ(8,  1, 1)
#undef TAPQ

    // ---- pass 1 load burst: 9 record reads, fenced ----
    const uint4 u0 = refk[(size_t)q0 * 8];
    const uint4 u1 = refk[(size_t)q1 * 8];
    const uint4 u2 = refk[(size_t)q2 * 8];
    const uint4 u3 = refk[(size_t)q3 * 8];
    const uint4 u4 = refk[(size_t)q4 * 8];
    const uint4 u5 = refk[(size_t)q5 * 8];
    const uint4 u6 = refk[(size_t)q6 * 8];
    const uint4 u7 = refk[(size_t)q7 * 8];
    const uint4 u8 = refk[(size_t)q8 * 8];

    // overlap LDS prefetch of the first pass-2 quads with the global burst
    int4 e = *(const int4*)&lists[lt][0];
    int4 f = *(const int4*)&lists[lt][4];
    const int Sreal = min(lcnt[lt], LCAP);
    const int S8 = (Sreal + 7) & ~7;

    __builtin_amdgcn_sched_barrier(0);   // nothing crosses: loads all issued

#define UNPACK(u_)                                                            \
    {                                                                         \
        a0 += __uint_as_float(u_.x << 16);                                    \
        a1 += __uint_as_float(u_.x & 0xffff0000u);                            \
        a2 += __uint_as_float(u_.y << 16);                                    \
        a3 += __uint_as_float(u_.y & 0xffff0000u);                            \
        a4 += __uint_as_float(u_.z << 16);                                    \
        a5 += __uint_as_float(u_.z & 0xffff0000u);                            \
        a6 += __uint_as_float(u_.w << 16);                                    \
        a7 += __uint_as_float(u_.w & 0xffff0000u);                            \
    }

    UNPACK(u0) UNPACK(u1) UNPACK(u2) UNPACK(u3) UNPACK(u4)
    UNPACK(u5) UNPACK(u6) UNPACK(u7) UNPACK(u8)

    // fold pass-1 into pass-2 scale domain: ws = 0.5*wr (exact pow2 scale)
    a0 *= 0.5f; a1 *= 0.5f; a2 *= 0.5f; a3 *= 0.5f;
    a4 *= 0.5f; a5 *= 0.5f; a6 *= 0.5f; a7 *= 0.5f;

    // ---- pass 2: 8-deep pipelined maskless walk (tails are SENT=zero) ----
    for (int s = 0; s < S8; s += 8) {
        const uint4 v0 = refk[(size_t)(e.x) * 8];
        const uint4 v1 = refk[(size_t)(e.y) * 8];
        const uint4 v2 = refk[(size_t)(e.z) * 8];
        const uint4 v3 = refk[(size_t)(e.w) * 8];
        const uint4 v4 = refk[(size_t)(f.x) * 8];
        const uint4 v5 = refk[(size_t)(f.y) * 8];
        const uint4 v6 = refk[(size_t)(f.z) * 8];
        const uint4 v7 = refk[(size_t)(f.w) * 8];
        const int4 en = *(const int4*)&lists[lt][s + 8];
        const int4 fn = *(const int4*)&lists[lt][s + 12];
        __builtin_amdgcn_sched_barrier(0);   // 8 loads in flight before use
        UNPACK(v0) UNPACK(v1) UNPACK(v2) UNPACK(v3)
        UNPACK(v4) UNPACK(v5) UNPACK(v6) UNPACK(v7)
        e = en; f = fn;
    }
#undef UNPACK

    // ---- epilogue: w = ws*nv + wr*Sreal (exact); LDS-transpose, then
    // full-line nt f32x4 stores (each wave: 8 channels x 128B runs) ----
    const float wsum = ws * (float)nv + wr * (float)Sreal;   // nv>=1 always
    const float sc = wr / wsum;
    obuf[8 * k + 0][lt] = a0 * sc;
    obuf[8 * k + 1][lt] = a1 * sc;
    obuf[8 * k + 2][lt] = a2 * sc;
    obuf[8 * k + 3][lt] = a3 * sc;
    obuf[8 * k + 4][lt] = a4 * sc;
    obuf[8 * k + 5][lt] = a5 * sc;
    obuf[8 * k + 6][lt] = a6 * sc;
    obuf[8 * k + 7][lt] = a7 * sc;
    __syncthreads();

#pragma unroll
    for (int it = 0; it < 2; ++it) {
        const int e2 = it * 256 + tid;       // 512 f32x4 = 64ch x 8 quads
        const int c  = e2 >> 3;              // channel
        const int qd = e2 & 7;               // target quad within the 32
        f32x4 v;
        v.x = obuf[c][4 * qd + 0];
        v.y = obuf[c][4 * qd + 1];
        v.z = obuf[c][4 * qd + 2];
        v.w = obuf[c][4 * qd + 3];
        // t0 = blockIdx*32 -> byte addr 128B-aligned; +16*qd keeps 16B align.
        __builtin_nontemporal_store(
            v, (f32x4*)(out + (size_t)c * HW + t0 + 4 * qd));
    }
}

// ===========================================================================
// Fallback (tiny workspace): bins only, gather channel-major f32 ref with
// the SEL-chain walk.  Unchanged from baseline (split cnt/slots layout).
// ===========================================================================
__global__ __launch_bounds__(256) void fill_bins(
    const int2* __restrict__ nnf_rs, int* __restrict__ cnt,
    int* __restrict__ slots)
{
    int r = blockIdx.x * 256 + threadIdx.x;
    int2 s = nnf_rs[r];
    int bin = (s.x << 9) | s.y;
    int pos = atomicAdd(&cnt[bin], 1);
    if (pos < KCAP) slots[(bin << 4) + pos] = r;
}

__global__ __launch_bounds__(256) void gather8_f32(
    const float* __restrict__ reff,
    const int2*  __restrict__ nnf_sr,
    const int*   __restrict__ cnt,
    const int*   __restrict__ slots,
    float* __restrict__ out)
{
    const float ws = 1.0f / 262144.0f;
    const float wr = 2.0f / 262144.0f;

    const int tid = threadIdx.x;
    const int k   = tid & 7;
    const int t   = blockIdx.x * 32 + (tid >> 3);
    const int ty  = t >> 9, tx = t & 511;

    float a0=0,a1=0,a2=0,a3=0,a4=0,a5=0,a6=0,a7=0, w=0.f;

#define ACCUM(qv, mv)                                                         \
    {                                                                         \
        const int   q_ = (qv);                                                \
        const float m_ = (mv);                                                \
        const size_t c0_ = (size_t)(8 * k) * HW + q_;                         \
        a0 += reff[c0_ + 0*(size_t)HW] * m_;                                  \
        a1 += reff[c0_ + 1*(size_t)HW] * m_;                                  \
        a2 += reff[c0_ + 2*(size_t)HW] * m_;                                  \
        a3 += reff[c0_ + 3*(size_t)HW] * m_;                                  \
        a4 += reff[c0_ + 4*(size_t)HW] * m_;                                  \
        a5 += reff[c0_ + 5*(size_t)HW] * m_;                                  \
        a6 += reff[c0_ + 6*(size_t)HW] * m_;                                  \
        a7 += reff[c0_ + 7*(size_t)HW] * m_;                                  \
        w += m_;                                                              \
    }

    int mt0,mt1,mt2,mt3,mt4,mt5,mt6,mt7,mt8;
    int run = 0;

#define TAP(i, dy, dx)                                                        \
    {                                                                         \
        const int sy = ty - (dy), sx = tx - (dx);                             \
        const bool sval = ((unsigned)sy < 512u) & ((unsigned)sx < 512u);      \
        const int sidx = ((sy & 511) << 9) | (sx & 511);                      \
        mt##i = (sidx << 12) | ((i) << 8) | run;                              \
        const int c = cnt[sidx];                                              \
        run += sval ? min(c, KCAP) : 0;                                       \
        const int2 nn = nnf_sr[sidx];                                         \
        const int qy = nn.x + (dy), qx = nn.y + (dx);                         \
        const bool v = sval & ((unsigned)qy < 512u) & ((unsigned)qx < 512u);  \
        ACCUM((((qy & 511) << 9) | (qx & 511)), v ? ws : 0.f)                 \
    }

    TAP(0, -1, -1)  TAP(1, -1, 0)  TAP(2, -1, 1)
    TAP(3,  0, -1)  TAP(4,  0, 0)  TAP(5,  0, 1)
    TAP(6,  1, -1)  TAP(7,  1, 0)  TAP(8,  1, 1)
#undef TAP

    const int S = run;

#define SEL(i)  m_ = (s_ >= (mt##i & 255)) ? mt##i : m_;
#define ENTRY(sv)                                                             \
    {                                                                         \
        const int s_ = (sv);                                                  \
        int m_ = mt0;                                                         \
        SEL(1) SEL(2) SEL(3) SEL(4) SEL(5) SEL(6) SEL(7) SEL(8)               \
        const int off_ = m_ & 255;                                            \
        const int ii_  = (m_ >> 8) & 15;                                      \
        const int bs_  = (m_ >> 12) << 4;                                     \
        const int idx_ = min(s_ - off_, KCAP - 1);                            \
        const int e_   = slots[bs_ + idx_];                                   \
        const int ry_  = (e_ >> 9) & 511, rx_ = e_ & 511;                     \
        const int dyp_ = (ii_ * 11) >> 5;                                     \
        const int dy_  = dyp_ - 1, dx_ = ii_ - 3 * dyp_ - 1;                  \
        const int qy_  = ry_ + dy_, qx_ = rx_ + dx_;                          \
        const bool v_  = (s_ < S) &                                           \
                         ((unsigned)qy_ < 512u) & ((unsigned)qx_ < 512u);     \
        ACCUM((((qy_ & 511) << 9) | (qx_ & 511)), v_ ? wr : 0.f)              \
    }

    for (int s = 0; s < S; s += 2) {
        ENTRY(s)
        ENTRY(s + 1)
    }
#undef ENTRY
#undef SEL
#undef ACCUM

    if (w == 0.f) w = 1.f;
    const float inv = 1.f / w;
    size_t o = (size_t)(8 * k) * HW + t;
    out[o]                = a0 * inv;
    out[o + 1*(size_t)HW] = a1 * inv;
    out[o + 2*(size_t)HW] = a2 * inv;
    out[o + 3*(size_t)HW] = a3 * inv;
    out[o + 4*(size_t)HW] = a4 * inv;
    out[o + 5*(size_t)HW] = a5 * inv;
    out[o + 6*(size_t)HW] = a6 * inv;
    out[o + 7*(size_t)HW] = a7 * inv;
}

extern "C" void kernel_launch(void* const* d_in, const int* in_sizes, int n_in,
                              void* d_out, int out_size, void* d_ws, size_t ws_size,
                              hipStream_t stream)
{
    const float* ref    = (const float*)d_in[0];
    const int2*  nnf_sr = (const int2*)d_in[1];
    const int2*  nnf_rs = (const int2*)d_in[2];
    float* out = (float*)d_out;

    char* wsb = (char*)d_ws;
    const size_t refT_bytes = (size_t)HW * NC * 2 + 128;  // +128B sentinel rec
    const size_t brec_bytes = (size_t)HW * 8 * 4;         //  8 MiB interleaved
    const size_t ovf_bytes  = (size_t)HW * NOVF * 4;      //  9 MiB overflow
    const size_t cnt_bytes  = (size_t)HW * 4;             //  1 MiB (fallback)
    const size_t slot_bytes = (size_t)HW * KCAP * 4;      // 16 MiB (fallback)

    if (ws_size >= refT_bytes + brec_bytes + ovf_bytes) {   // ~49.3 MiB
        uint4* refu4  = (uint4*)wsb;
        int*   binrec = (int*)(wsb + refT_bytes);
        int*   ovf    = (int*)(wsb + refT_bytes + brec_bytes);

        (void)hipMemsetAsync(binrec, 0, brec_bytes, stream);
        prep_fill<<<4096 + HW / 256, 256, 0, stream>>>(
            (const float4*)ref, refu4, nnf_rs, binrec, ovf);
        gather_lds<<<HW / 32, 256, 0, stream>>>(refu4, nnf_sr, binrec, ovf, out);
    } else {
        // fallback: bins only, gather channel-major f32 ref directly
        int* cntp  = (int*)wsb;
        int* slots = cntp + HW;
        (void)hipMemsetAsync(cntp, 0, cnt_bytes, stream);
        fill_bins<<<HW / 256, 256, 0, stream>>>(nnf_rs, cntp, slots);
        gather8_f32<<<HW / 32, 256, 0, stream>>>(ref, nnf_sr, cntp, slots, out);
    }
}